// Round 5
// baseline (21668.687 us; speedup 1.0000x reference)
//
#include <hip/hip_runtime.h>

#define S_LEN 16384
#define BATCH 128
#define HID   128
#define CHUNK 64
#define NCHUNK (S_LEN / CHUNK)

typedef float f2 __attribute__((ext_vector_type(2)));

// tanh(z) = (e^{2z}-1)/(e^{2z}+1), e^{2z} = exp2(2*log2(e)*z).
// Clamp |z|<=9: tanh(9) = 1 - 2.7e-8 (< fp32 resolution of 1.0).
__device__ __forceinline__ float fast_tanh(float z) {
    z = fminf(fmaxf(z, -9.0f), 9.0f);
    float e = __builtin_amdgcn_exp2f(z * 2.8853900817779268f); // 2*log2(e)
    return (e - 1.0f) * __builtin_amdgcn_rcpf(e + 1.0f);
}

#define REP32(M) M(0) M(1) M(2) M(3) M(4) M(5) M(6) M(7) \
                 M(8) M(9) M(10) M(11) M(12) M(13) M(14) M(15) \
                 M(16) M(17) M(18) M(19) M(20) M(21) M(22) M(23) \
                 M(24) M(25) M(26) M(27) M(28) M(29) M(30) M(31)

// ONE WAVE per batch chain (128 blocks x 64 threads). Zero s_barriers:
// a 64-thread block's __syncthreads() is elided to a waitcnt (single wave
// is lockstep). Lane l owns hidden units jA=l and jB=l+64 with FULL K=128;
// the 256 weights live as 128 pinned VGPR pairs and the matvec runs as
// 128 v_pk_fma_f32 (gfx950 full-rate packed fp32). Round-4's 2 eight-wave
// barriers + 2 LDS round-trips (~600 cyc/step of drain) are gone.
__global__ __launch_bounds__(64, 1) void ode_scan_kernel(
    const float* __restrict__ x,
    const float* __restrict__ W1, const float* __restrict__ b1,
    const float* __restrict__ W2, const float* __restrict__ b2,
    const float* __restrict__ W3, const float* __restrict__ b3,
    float* __restrict__ out)
{
    const int l  = threadIdx.x;      // lane
    const int bb = blockIdx.x;       // batch chain index
    const int jA = l;                // first owned hidden unit
    const int jB = l + 64;           // second owned hidden unit

    __shared__ __align__(16) float lds_h[HID];
    __shared__ float lds_x[2][CHUNK];

    const float c1A = W1[jA],       c1B = W1[jB];
    const float w1A = W1[HID + jA], w1B = W1[HID + jB];
    const float b1A = b1[jA],       b1B = b1[jB];
    const float b2A = b2[jA],       b2B = b2[jB];
    const float w3A = W3[jA],       w3B = W3[jB];
    const float b3s = b3[0];

    // 256 weights (2 units x K=128) as 128 named f32x2 pairs, pinned.
    // Row loads W2[i*HID + j] are coalesced across lanes (j = l / l+64).
#define DECLW(r) \
    f2 wa_##r##_0 = { W2[(4*(r)+0)*HID + jA], W2[(4*(r)+1)*HID + jA] }; \
    f2 wa_##r##_1 = { W2[(4*(r)+2)*HID + jA], W2[(4*(r)+3)*HID + jA] }; \
    f2 wb_##r##_0 = { W2[(4*(r)+0)*HID + jB], W2[(4*(r)+1)*HID + jB] }; \
    f2 wb_##r##_1 = { W2[(4*(r)+2)*HID + jB], W2[(4*(r)+3)*HID + jB] }; \
    asm volatile("" : "+v"(wa_##r##_0), "+v"(wa_##r##_1), \
                      "+v"(wb_##r##_0), "+v"(wb_##r##_1));
    REP32(DECLW)

    // Preload x chunk 0: lds_x[0][t] = x[t][bb].
    lds_x[0][l] = x[l * BATCH + bb];
    __syncthreads();

    float y    = 0.0f;
    float ycap = 0.0f;
    float xc   = lds_x[0][0];
    int   cur  = 0;

    const f2* lh2 = (const f2*)lds_h;

    for (int c = 0; c < NCHUNK; ++c) {
        // Refill other buffer with next chunk (dup-load last chunk, unused).
        int nb = (c + 1 < NCHUNK) ? (c + 1) : c;
        float xf = x[(nb * CHUNK + l) * BATCH + bb];
        lds_x[cur ^ 1][l] = xf;

#pragma unroll 1
        for (int s = 0; s < CHUNK; ++s) {
            float xn = (s < CHUNK - 1) ? lds_x[cur][s + 1] : lds_x[cur ^ 1][0];

            // ---- layer 1: two owned units (ILP 2) ----
            float h1A = fast_tanh(fmaf(c1A, y, fmaf(w1A, xc, b1A)));
            float h1B = fast_tanh(fmaf(c1B, y, fmaf(w1B, xc, b1B)));
            lds_h[jA] = h1A;
            lds_h[jB] = h1B;
            __syncthreads();             // single wave: waitcnt only, no barrier

            // ---- layer 2: full-K matvec, 128 v_pk_fma_f32 ----
            f2 aA0 = {0.0f, 0.0f}, aA1 = {0.0f, 0.0f};
            f2 aB0 = {0.0f, 0.0f}, aB1 = {0.0f, 0.0f};
#define MAC(r) { \
            f2 h01 = lh2[2*(r)];     /* broadcast ds_read */ \
            f2 h23 = lh2[2*(r)+1]; \
            aA0 = __builtin_elementwise_fma(h01, wa_##r##_0, aA0); \
            aA1 = __builtin_elementwise_fma(h23, wa_##r##_1, aA1); \
            aB0 = __builtin_elementwise_fma(h01, wb_##r##_0, aB0); \
            aB1 = __builtin_elementwise_fma(h23, wb_##r##_1, aB1); }
            REP32(MAC)

            float sA = ((aA0.x + aA0.y) + (aA1.x + aA1.y)) + b2A;
            float sB = ((aB0.x + aB0.y) + (aB1.x + aB1.y)) + b2B;
            float h2A = fast_tanh(sA);
            float h2B = fast_tanh(sB);
            float p   = fmaf(h2A, w3A, h2B * w3B);

            // ---- layer 3: 64-lane DPP sum (result in lane 63) ----
            asm volatile(
                "s_nop 1\n\t"
                "v_add_f32 %0, %0, %0 row_shr:1 bound_ctrl:0\n\t"
                "s_nop 1\n\t"
                "v_add_f32 %0, %0, %0 row_shr:2 bound_ctrl:0\n\t"
                "s_nop 1\n\t"
                "v_add_f32 %0, %0, %0 row_shr:4 bank_mask:0xe\n\t"
                "s_nop 1\n\t"
                "v_add_f32 %0, %0, %0 row_shr:8 bank_mask:0xc\n\t"
                "s_nop 1\n\t"
                "v_add_f32 %0, %0, %0 row_bcast:15 row_mask:0xa\n\t"
                "s_nop 1\n\t"
                "v_add_f32 %0, %0, %0 row_bcast:31 row_mask:0xc\n\t"
                : "+v"(p));

            float sv;
            asm volatile(
                "s_nop 1\n\t"
                "v_readlane_b32 %0, %1, 63\n\t"
                "s_nop 1"
                : "=s"(sv) : "v"(p));

            y = y + (sv + b3s);              // y_{n+1}, wave-uniform

            ycap = (l == s) ? y : ycap;      // lane s captures ys[c*64+s]
            xc = xn;
        }

        out[(c * CHUNK + l) * BATCH + bb] = ycap;   // 64 steps per store
        cur ^= 1;
    }
}

extern "C" void kernel_launch(void* const* d_in, const int* in_sizes, int n_in,
                              void* d_out, int out_size, void* d_ws, size_t ws_size,
                              hipStream_t stream) {
    const float* x  = (const float*)d_in[0];
    const float* W1 = (const float*)d_in[1];
    const float* b1 = (const float*)d_in[2];
    const float* W2 = (const float*)d_in[3];
    const float* b2 = (const float*)d_in[4];
    const float* W3 = (const float*)d_in[5];
    const float* b3 = (const float*)d_in[6];
    float* out = (float*)d_out;

    hipLaunchKernelGGL(ode_scan_kernel, dim3(BATCH), dim3(64), 0, stream,
                       x, W1, b1, W2, b2, W3, b3, out);
}

// Round 6
// 8893.780 us; speedup vs baseline: 2.4364x; 2.4364x over previous
//
#include <hip/hip_runtime.h>

#define S_LEN 16384
#define BATCH 128
#define HID   128
#define NTHR  128
#define CHUNK 128
#define NCHUNK (S_LEN / CHUNK)

typedef float f2 __attribute__((ext_vector_type(2)));

// tanh(z) = (e^{2z}-1)/(e^{2z}+1), e^{2z} = exp2(2*log2(e)*z).
// Clamp |z|<=9: tanh(9) = 1 - 2.7e-8 (< fp32 resolution of 1.0).
__device__ __forceinline__ float fast_tanh(float z) {
    z = fminf(fmaxf(z, -9.0f), 9.0f);
    float e = __builtin_amdgcn_exp2f(z * 2.8853900817779268f); // 2*log2(e)
    return (e - 1.0f) * __builtin_amdgcn_rcpf(e + 1.0f);
}

#define REP16(M) M(0) M(1) M(2) M(3) M(4) M(5) M(6) M(7) \
                 M(8) M(9) M(10) M(11) M(12) M(13) M(14) M(15)

// One block = one chain, 128 threads = 2 waves.
// K is split ACROSS waves (wave w owns K-half [64w,64w+64)), units within
// the wave (lane l owns units jA=l, jB=l+64 for its K-half: 128 weights =
// 64 f2 pairs -> ~170 live VGPRs, fits the 256 cap; round-5 spilled at 256+).
// h1 exchange is wave-internal (in-order DS, no barrier). The only barrier
// per step is the cross-wave partial exchange, double-buffered by step
// parity to kill the WAR race across a single barrier. Both waves then
// redundantly finish layers 2-3 (tanh, W3 dot, DPP reduce, readlane) ->
// bit-identical y in all 128 threads.
__global__ __launch_bounds__(NTHR, 1) void ode_scan_kernel(
    const float* __restrict__ x,
    const float* __restrict__ W1, const float* __restrict__ b1,
    const float* __restrict__ W2, const float* __restrict__ b2,
    const float* __restrict__ W3, const float* __restrict__ b3,
    float* __restrict__ out)
{
    const int tid  = threadIdx.x;    // = 64*w + l; also layer-1 row index i
    const int bb   = blockIdx.x;     // batch chain index
    const int l    = tid & 63;       // lane: owned units jA=l, jB=l+64
    const int w    = tid >> 6;       // wave: K-half [64w, 64w+64)
    const int koff = w << 6;

    __shared__ __align__(16) float lds_hw[2][64];   // per-wave h1 half
    __shared__ __align__(16) f2    lds_p[2][HID];   // [buf][unit]={p_w0,p_w1}
    __shared__ float lds_x[2][CHUNK];

    // layer-1 constants for K-row i = tid
    const float c1  = W1[tid];          // y coefficient (row 0)
    const float w1x = W1[HID + tid];    // x coefficient (row 1)
    const float b1i = b1[tid];
    // layer-2/3 constants for the two owned units
    const float b2A = b2[l],  b2B = b2[l + 64];
    const float w3A = W3[l],  w3B = W3[l + 64];
    const float b3s = b3[0];

    // 128 weights: W2[koff+4r+t][jA/jB], t=0..3, as 64 named f2 pairs.
#define DECLW(r) \
    f2 wA##r##0 = { W2[(koff+4*(r)+0)*HID + l],      W2[(koff+4*(r)+1)*HID + l] }; \
    f2 wA##r##1 = { W2[(koff+4*(r)+2)*HID + l],      W2[(koff+4*(r)+3)*HID + l] }; \
    f2 wB##r##0 = { W2[(koff+4*(r)+0)*HID + l + 64], W2[(koff+4*(r)+1)*HID + l + 64] }; \
    f2 wB##r##1 = { W2[(koff+4*(r)+2)*HID + l + 64], W2[(koff+4*(r)+3)*HID + l + 64] }; \
    asm volatile("" : "+v"(wA##r##0), "+v"(wA##r##1), "+v"(wB##r##0), "+v"(wB##r##1));
    REP16(DECLW)

    // Preload x chunk 0: lds_x[0][t] = x[t][bb].
    lds_x[0][tid] = x[tid * BATCH + bb];
    __syncthreads();

    float y = 0.0f, ycap = 0.0f;
    float ax  = fmaf(w1x, lds_x[0][0], b1i);   // layer-1 y-independent part
    int   cur = 0;

    const float4* lh4 = (const float4*)lds_hw[w];   // own wave's h-half

    for (int c = 0; c < NCHUNK; ++c) {
        // Refill other x buffer with next chunk (dup-load last, unused).
        int nb = (c + 1 < NCHUNK) ? (c + 1) : c;
        float xf = x[(nb * CHUNK + tid) * BATCH + bb];
        lds_x[cur ^ 1][tid] = xf;

#pragma unroll 1
        for (int s = 0; s < CHUNK; ++s) {
            float xn  = (s < CHUNK - 1) ? lds_x[cur][s + 1] : lds_x[cur ^ 1][0];
            float axn = fmaf(w1x, xn, b1i);    // next step's y-independent part

            // ---- layer 1 for K-row i=tid (wave-local h-half) ----
            float h1 = fast_tanh(fmaf(c1, y, ax));
            lds_hw[w][l] = h1;                 // wave-internal: in-order DS,
                                               // no barrier needed
            // ---- layer 2: half-K x 2 units, 64 v_pk_fma_f32 ----
            f2 aA0 = {0.f,0.f}, aA1 = {0.f,0.f}, aB0 = {0.f,0.f}, aB1 = {0.f,0.f};
#define MAC(r) { float4 h = lh4[r]; \
            f2 h01 = { h.x, h.y }, h23 = { h.z, h.w }; \
            aA0 = __builtin_elementwise_fma(h01, wA##r##0, aA0); \
            aA1 = __builtin_elementwise_fma(h23, wA##r##1, aA1); \
            aB0 = __builtin_elementwise_fma(h01, wB##r##0, aB0); \
            aB1 = __builtin_elementwise_fma(h23, wB##r##1, aB1); }
            REP16(MAC)

            float pA = (aA0.x + aA0.y) + (aA1.x + aA1.y);
            float pB = (aB0.x + aB0.y) + (aB1.x + aB1.y);

            // ---- publish partials; the ONE barrier per step ----
            const int buf = s & 1;             // double-buffer: WAR-safe
            float* pb = (float*)&lds_p[buf][0];
            pb[2 * l + w]        = pA;         // banks (2l+w)%32: 2 lanes/bank
            pb[2 * (l + 64) + w] = pB;
            __syncthreads();

            // ---- finish: both waves redundantly, bit-identical ----
            f2 PA = lds_p[buf][l];             // {wave0, wave1} partials
            f2 PB = lds_p[buf][l + 64];
            float h2A = fast_tanh((PA.x + PA.y) + b2A);
            float h2B = fast_tanh((PB.x + PB.y) + b2B);
            float qv  = fmaf(h2A, w3A, h2B * w3B);

            // 64-lane DPP sum (covers all 128 units) -> lane 63
            asm volatile(
                "s_nop 1\n\t"
                "v_add_f32 %0, %0, %0 row_shr:1 bound_ctrl:0\n\t"
                "s_nop 1\n\t"
                "v_add_f32 %0, %0, %0 row_shr:2 bound_ctrl:0\n\t"
                "s_nop 1\n\t"
                "v_add_f32 %0, %0, %0 row_shr:4 bank_mask:0xe\n\t"
                "s_nop 1\n\t"
                "v_add_f32 %0, %0, %0 row_shr:8 bank_mask:0xc\n\t"
                "s_nop 1\n\t"
                "v_add_f32 %0, %0, %0 row_bcast:15 row_mask:0xa\n\t"
                "s_nop 1\n\t"
                "v_add_f32 %0, %0, %0 row_bcast:31 row_mask:0xc\n\t"
                : "+v"(qv));
            float sv;
            asm volatile(
                "s_nop 1\n\t"
                "v_readlane_b32 %0, %1, 63\n\t"
                "s_nop 1"
                : "=s"(sv) : "v"(qv));

            y = y + (sv + b3s);                // y_{n+1}, wave-uniform
            ycap = (tid == s) ? y : ycap;      // thread s captures ys[c*128+s]
            ax = axn;
        }
        out[(c * CHUNK + tid) * BATCH + bb] = ycap;   // 128 steps per store
        cur ^= 1;
    }
}

extern "C" void kernel_launch(void* const* d_in, const int* in_sizes, int n_in,
                              void* d_out, int out_size, void* d_ws, size_t ws_size,
                              hipStream_t stream) {
    const float* x  = (const float*)d_in[0];
    const float* W1 = (const float*)d_in[1];
    const float* b1 = (const float*)d_in[2];
    const float* W2 = (const float*)d_in[3];
    const float* b2 = (const float*)d_in[4];
    const float* W3 = (const float*)d_in[5];
    const float* b3 = (const float*)d_in[6];
    float* out = (float*)d_out;

    hipLaunchKernelGGL(ode_scan_kernel, dim3(BATCH), dim3(NTHR), 0, stream,
                       x, W1, b1, W2, b2, W3, b3, out);
}